// Round 4
// baseline (504.177 us; speedup 1.0000x reference)
//
#include <hip/hip_runtime.h>

#define TTOT 16384   // 4 * 4096 tokens
#define DDIM 2048
#define NEXP 64
#define KC   32      // K chunk: W held in VGPRs, x streamed via vector loads
#define TPW  4       // tokens per wave
#define WPB  4       // waves per block -> grid 1024, 16 waves/CU

// lane = expert (64 experts = 64 lanes). W[d][lane] per-lane coalesced ->
// VGPR-resident per chunk. x[tok][d] is wave-uniform but loaded via VECTOR
// loads (uniform address -> 1 L1 line, broadcast to all lanes): unlike
// s_load (SMEM completes out-of-order -> compiler must lgkmcnt(0) before
// every use), vector loads pipeline via fine-grained vmcnt(N). The mbcnt
// offset is provably 0 but divergent to LLVM -> forces VMEM path.
__global__ __launch_bounds__(256, 4)
void moe_router(const float* __restrict__ x, const float* __restrict__ W,
                float* __restrict__ out)
{
    const int lane = threadIdx.x & 63;
    const int wq   = __builtin_amdgcn_readfirstlane(threadIdx.x >> 6);
    const int tok0 = (blockIdx.x * WPB + wq) * TPW;

    // == 0 in every lane, but opaque/divergent -> keeps x loads on VMEM path
    const int vz = __builtin_amdgcn_mbcnt_lo(0u, 0u);

    const float* Wl  = W + lane;                      // lane's expert column
    const float* xr0 = x + (size_t)tok0 * DDIM + vz;  // divergent-tagged base

    double acc64[TPW];
#pragma unroll
    for (int t = 0; t < TPW; ++t) acc64[t] = 0.0;

    for (int kb = 0; kb < DDIM; kb += KC) {
        // W chunk -> VGPRs (coalesced 256B per d, reused by TPW tokens, L1-hot)
        float w[KC];
#pragma unroll
        for (int j = 0; j < KC; ++j)
            w[j] = Wl[(size_t)(kb + j) * NEXP];

        // 2-stage software pipeline over tokens: load t+1 while FMAing t
        float4 xb[2][KC / 4];
#pragma unroll
        for (int j = 0; j < KC / 4; ++j)
            xb[0][j] = *(const float4*)(xr0 + kb + 4 * j);

#pragma unroll
        for (int t = 0; t < TPW; ++t) {
            if (t + 1 < TPW) {
                const float* xn = xr0 + (size_t)(t + 1) * DDIM + kb;
#pragma unroll
                for (int j = 0; j < KC / 4; ++j)
                    xb[(t + 1) & 1][j] = *(const float4*)(xn + 4 * j);
            }
            const float4* xv = xb[t & 1];
            // 4 independent fp32 chains (FMA latency), fp64 across chunks:
            // top-2 indices must match the np reference exactly.
            float a0 = 0.0f, a1 = 0.0f, a2 = 0.0f, a3 = 0.0f;
#pragma unroll
            for (int j = 0; j < KC / 4; ++j) {
                a0 = fmaf(xv[j].x, w[4 * j + 0], a0);
                a1 = fmaf(xv[j].y, w[4 * j + 1], a1);
                a2 = fmaf(xv[j].z, w[4 * j + 2], a2);
                a3 = fmaf(xv[j].w, w[4 * j + 3], a3);
            }
            acc64[t] += (double)((a0 + a1) + (a2 + a3));
        }
    }

    float* dispatch = out;
    float* probs    = out + (size_t)TTOT * NEXP;
    float* tkp      = out + (size_t)2 * TTOT * NEXP;
    float* tki      = tkp + (size_t)TTOT * 2;

    // logits sit lane=expert: softmax + top-2 per token via shuffles
#pragma unroll
    for (int t = 0; t < TPW; ++t) {
        const int gt  = tok0 + t;
        const float L = (float)acc64[t];

        float m = L;
#pragma unroll
        for (int off = 32; off; off >>= 1) m = fmaxf(m, __shfl_xor(m, off, 64));
        const float p = expf(L - m);
        float s = p;
#pragma unroll
        for (int off = 32; off; off >>= 1) s += __shfl_xor(s, off, 64);
        const float prob = p / s;

        // top-1 (ties -> lowest index, matching lax.top_k / np)
        float v1 = prob; int i1 = lane;
#pragma unroll
        for (int off = 32; off; off >>= 1) {
            const float ov = __shfl_xor(v1, off, 64);
            const int   oi = __shfl_xor(i1, off, 64);
            if (ov > v1 || (ov == v1 && oi < i1)) { v1 = ov; i1 = oi; }
        }
        // top-2
        float v2 = (lane == i1) ? -1.0f : prob; int i2 = lane;
#pragma unroll
        for (int off = 32; off; off >>= 1) {
            const float ov = __shfl_xor(v2, off, 64);
            const int   oi = __shfl_xor(i2, off, 64);
            if (ov > v2 || (ov == v2 && oi < i2)) { v2 = ov; i2 = oi; }
        }

        probs[(size_t)gt * NEXP + lane]    = prob;
        dispatch[(size_t)gt * NEXP + lane] = (lane == i1 || lane == i2) ? 1.0f : 0.0f;
        if (lane == 0) {
            tkp[(size_t)gt * 2 + 0] = v1;
            tkp[(size_t)gt * 2 + 1] = v2;
            tki[(size_t)gt * 2 + 0] = (float)i1;
            tki[(size_t)gt * 2 + 1] = (float)i2;
        }
    }
}

extern "C" void kernel_launch(void* const* d_in, const int* in_sizes, int n_in,
                              void* d_out, int out_size, void* d_ws, size_t ws_size,
                              hipStream_t stream) {
    const float* x = (const float*)d_in[0];
    const float* W = (const float*)d_in[1];
    float* out = (float*)d_out;
    moe_router<<<TTOT / (TPW * WPB), 256, 0, stream>>>(x, W, out);
}